// Round 9
// baseline (40.342 us; speedup 1.0000x reference)
//
#include <hip/hip_runtime.h>

typedef __fp16   pk16x2 __attribute__((ext_vector_type(2)));
typedef _Float16 f16x8  __attribute__((ext_vector_type(8)));
typedef float    f32x4  __attribute__((ext_vector_type(4)));
typedef float    f32x16 __attribute__((ext_vector_type(16)));

#define BATCH 65536
#define NIN   128
#define NOUT  128

#define L2E   1.4426950408889634f
#define SQL2E 1.2011224087864498f     /* sqrt(log2 e) */
#define EM2   0.1353352832366127f     /* e^-2 */

// ---------------------------------------------------------------------------
// Persistent-W structure. MFMA 32x32x16 f16.
// A-frag: lane -> row = l&31, k = (l>>5)*8 + e.  B-frag: col = l&31, same k.
// C/D: col = l&31, row = (reg&3) + 8*(reg>>2) + 4*(l>>5).
//
// 72 ksteps of 16, grouped 8 x 9: group g = {8 basis ksteps q=0..7, 1 silu}.
//   basis kstep (g,q): k-slot sub*8+e -> j = g*16 + sub*8 + q, grid = e
//   silu  kstep (g):   k-slot sub*8+e -> j = g*16 + sub*8 + e
// => lane's x for the WHOLE group g = x[row][g*16 + sub*8 .. +7] (2 f32x4),
//    each x float loaded exactly once per lane.
//
// W4 (kan_prep, 288 KB): two col-halves h=0,1 of 144 KB; within half:
//   chunk i = kk*128 + c2 (16 B), kk = g*9 + q, c2 = nbb2*64 + lane2:
//   col = h*64 + nbb2*32 + (lane2&31), sub = lane2>>5:
//     q<8 : coeffs[col][g*16 + sub*8 + q][e]
//     q==8: base_w[col][g*16 + sub*8 + e]
// Block stages its half ONCE into LDS (linear, coalesced); per-kstep
// fragment ds_read = 64 lanes x 16 B consecutive -> conflict-free.
// ---------------------------------------------------------------------------

__global__ __launch_bounds__(256) void kan_prep(const float* __restrict__ coeffs,
                                                const float* __restrict__ base_w,
                                                _Float16* __restrict__ W4) {
    int t = blockIdx.x * 256 + threadIdx.x;   // chunk id, 0..18431
    int h    = t / 9216;
    int rem  = t - h * 9216;
    int kk   = rem >> 7;
    int c2   = rem & 127;
    int g    = kk / 9;
    int q    = kk - g * 9;
    int nbb2 = c2 >> 6;
    int lane2 = c2 & 63;
    int sub  = lane2 >> 5;
    int col  = h * 64 + nbb2 * 32 + (lane2 & 31);
    const float* src = (q < 8)
        ? coeffs + ((size_t)col * 128 + g * 16 + sub * 8 + q) * 8
        : base_w + (size_t)col * 128 + g * 16 + sub * 8;
    f16x8 v;
#pragma unroll
    for (int e = 0; e < 8; ++e) v[e] = (_Float16)src[e];
    *(f16x8*)((char*)W4 + (size_t)t * 16) = v;
}

__device__ __forceinline__ void gll16(const void* g, void* l) {
    __builtin_amdgcn_global_load_lds(
        (const __attribute__((address_space(1))) unsigned int*)g,
        (__attribute__((address_space(3))) unsigned int*)l, 16, 0, 0);
}

// b_g = exp(-(t-g)^2), t = 3.5*(x+1): 2 exp + mul chain, pkrtz packing.
__device__ __forceinline__ f16x8 basis8r(float t) {
    float u  = t * SQL2E;
    float b0 = __builtin_amdgcn_exp2f(-(u * u));                              // e^{-t^2}
    float r  = __builtin_amdgcn_exp2f(__builtin_fmaf(t, 2.0f * L2E, -L2E));   // e^{2t-1}
    float b1 = b0 * r; r *= EM2;
    float b2 = b1 * r; r *= EM2;
    float b3 = b2 * r; r *= EM2;
    float b4 = b3 * r; r *= EM2;
    float b5 = b4 * r; r *= EM2;
    float b6 = b5 * r; r *= EM2;
    float b7 = b6 * r;
    pk16x2 p0 = __builtin_amdgcn_cvt_pkrtz(b0, b1);
    pk16x2 p1 = __builtin_amdgcn_cvt_pkrtz(b2, b3);
    pk16x2 p2 = __builtin_amdgcn_cvt_pkrtz(b4, b5);
    pk16x2 p3 = __builtin_amdgcn_cvt_pkrtz(b6, b7);
    f16x8 o;
    o[0] = p0[0]; o[1] = p0[1]; o[2] = p1[0]; o[3] = p1[1];
    o[4] = p2[0]; o[5] = p2[1]; o[6] = p3[0]; o[7] = p3[1];
    return o;
}

__device__ __forceinline__ float silu1(float xv) {
    float p = __builtin_amdgcn_exp2f(-xv * L2E);
    return xv * __builtin_amdgcn_rcpf(1.0f + p);
}

// 512 threads = 8 waves, each 64 rows x 64 cols (m=2, nbb=2). Block = 512
// rows x one 64-col half; W half (144 KB) persistent in LDS. ONE barrier
// total; waves free-run so VALU/trans/LDS/matrix pipes overlap across the
// 8 waves/CU (2/SIMD at <=256 VGPR). Grid 256 = 1 block/CU; blocks 2r,2r+1
// are the two col-halves of the same rows (adjacent dispatch -> x L3 reuse).
__global__ __launch_bounds__(512, 1) void kan_main(const float* __restrict__ x,
                                                   const _Float16* __restrict__ W4,
                                                   float* __restrict__ out) {
    extern __shared__ _Float16 smem[];   // 147456 B = 72 ksteps x 2 KB

    const int tid  = threadIdx.x;
    const int lane = tid & 63;
    const int w    = tid >> 6;
    const int l31  = lane & 31;
    const int sub  = lane >> 5;
    const int h    = blockIdx.x & 1;
    const int row0 = (blockIdx.x >> 1) * 512 + w * 64;
    const int col0 = h * 64;

    // ---- stage this col-half's W once: 9216 chunks, linear & coalesced ----
    const char* ws = (const char*)W4 + (size_t)h * 147456;
    char*       ls = (char*)smem;
#pragma unroll
    for (int i = 0; i < 18; ++i)
        gll16(ws + (size_t)(i * 512 + tid) * 16, ls + (size_t)(i * 512 + tid) * 16);

    const float* xp = x + (size_t)(row0 + l31) * NIN;   // lane's x row (m=0)

    f32x16 acc[2][2];
#pragma unroll
    for (int m = 0; m < 2; ++m)
#pragma unroll
        for (int nbb = 0; nbb < 2; ++nbb)
#pragma unroll
            for (int r = 0; r < 16; ++r) acc[m][nbb][r] = 0.f;

    // group-0 x: lane's 8 floats per m  (m=1 -> +32 rows = +4096 floats)
    f32x4 xc00 = *(const f32x4*)(xp + sub * 8);
    f32x4 xc01 = *(const f32x4*)(xp + sub * 8 + 4);
    f32x4 xc10 = *(const f32x4*)(xp + 4096 + sub * 8);
    f32x4 xc11 = *(const f32x4*)(xp + 4096 + sub * 8 + 4);

    __syncthreads();   // the only barrier

#define MFMA4(A0, A1, BP)                                                        \
    do {                                                                         \
        f16x8 _b0 = *(const f16x8*)(BP);                                         \
        f16x8 _b1 = *(const f16x8*)((BP) + 1024);                                \
        acc[0][0] = __builtin_amdgcn_mfma_f32_32x32x16_f16(A0, _b0, acc[0][0], 0, 0, 0); \
        acc[0][1] = __builtin_amdgcn_mfma_f32_32x32x16_f16(A0, _b1, acc[0][1], 0, 0, 0); \
        acc[1][0] = __builtin_amdgcn_mfma_f32_32x32x16_f16(A1, _b0, acc[1][0], 0, 0, 0); \
        acc[1][1] = __builtin_amdgcn_mfma_f32_32x32x16_f16(A1, _b1, acc[1][1], 0, 0, 0); \
    } while (0)

#pragma unroll
    for (int g = 0; g < 8; ++g) {
        const int kb = g * 9;
        // prefetch next group's x
        f32x4 xn00, xn01, xn10, xn11;
        if (g < 7) {
            const float* np = xp + (g + 1) * 16 + sub * 8;
            xn00 = *(const f32x4*)np;
            xn01 = *(const f32x4*)(np + 4);
            xn10 = *(const f32x4*)(np + 4096);
            xn11 = *(const f32x4*)(np + 4100);
        }
        // half-group 0: ksteps kb+0..3  (8 independent basis chains)
        {
            f16x8 a0[4], a1[4];
#pragma unroll
            for (int t2 = 0; t2 < 4; ++t2) {
                a0[t2] = basis8r(__builtin_fmaf(xc00[t2], 3.5f, 3.5f));
                a1[t2] = basis8r(__builtin_fmaf(xc10[t2], 3.5f, 3.5f));
            }
#pragma unroll
            for (int t2 = 0; t2 < 4; ++t2) {
                const char* bp = ls + (size_t)(kb + t2) * 2048 + lane * 16;
                MFMA4(a0[t2], a1[t2], bp);
            }
        }
        // half-group 1: ksteps kb+4..7
        {
            f16x8 a0[4], a1[4];
#pragma unroll
            for (int t2 = 0; t2 < 4; ++t2) {
                a0[t2] = basis8r(__builtin_fmaf(xc01[t2], 3.5f, 3.5f));
                a1[t2] = basis8r(__builtin_fmaf(xc11[t2], 3.5f, 3.5f));
            }
#pragma unroll
            for (int t2 = 0; t2 < 4; ++t2) {
                const char* bp = ls + (size_t)(kb + 4 + t2) * 2048 + lane * 16;
                MFMA4(a0[t2], a1[t2], bp);
            }
        }
        // silu kstep kb+8, reusing the group's x registers
        {
            float s0 = silu1(xc00[0]), s1 = silu1(xc00[1]), s2 = silu1(xc00[2]), s3 = silu1(xc00[3]);
            float s4 = silu1(xc01[0]), s5 = silu1(xc01[1]), s6 = silu1(xc01[2]), s7 = silu1(xc01[3]);
            pk16x2 p0 = __builtin_amdgcn_cvt_pkrtz(s0, s1);
            pk16x2 p1 = __builtin_amdgcn_cvt_pkrtz(s2, s3);
            pk16x2 p2 = __builtin_amdgcn_cvt_pkrtz(s4, s5);
            pk16x2 p3 = __builtin_amdgcn_cvt_pkrtz(s6, s7);
            f16x8 a0;
            a0[0] = p0[0]; a0[1] = p0[1]; a0[2] = p1[0]; a0[3] = p1[1];
            a0[4] = p2[0]; a0[5] = p2[1]; a0[6] = p3[0]; a0[7] = p3[1];
            float u0 = silu1(xc10[0]), u1 = silu1(xc10[1]), u2 = silu1(xc10[2]), u3 = silu1(xc10[3]);
            float u4 = silu1(xc11[0]), u5 = silu1(xc11[1]), u6 = silu1(xc11[2]), u7 = silu1(xc11[3]);
            pk16x2 q0 = __builtin_amdgcn_cvt_pkrtz(u0, u1);
            pk16x2 q1 = __builtin_amdgcn_cvt_pkrtz(u2, u3);
            pk16x2 q2 = __builtin_amdgcn_cvt_pkrtz(u4, u5);
            pk16x2 q3 = __builtin_amdgcn_cvt_pkrtz(u6, u7);
            f16x8 a1;
            a1[0] = q0[0]; a1[1] = q0[1]; a1[2] = q1[0]; a1[3] = q1[1];
            a1[4] = q2[0]; a1[5] = q2[1]; a1[6] = q3[0]; a1[7] = q3[1];
            const char* bp = ls + (size_t)(kb + 8) * 2048 + lane * 16;
            MFMA4(a0, a1, bp);
        }
        if (g < 7) { xc00 = xn00; xc01 = xn01; xc10 = xn10; xc11 = xn11; }
    }

    // ---- Epilogue: row = (r&3) + 8*(r>>2) + 4*sub, col = col0 + nbb*32 + l31
#pragma unroll
    for (int m = 0; m < 2; ++m)
#pragma unroll
        for (int nbb = 0; nbb < 2; ++nbb)
#pragma unroll
            for (int r = 0; r < 16; ++r) {
                int crow = (r & 3) + 8 * (r >> 2) + 4 * sub;
                out[(size_t)(row0 + m * 32 + crow) * NOUT + col0 + nbb * 32 + l31] = acc[m][nbb][r];
            }
}

extern "C" void kernel_launch(void* const* d_in, const int* in_sizes, int n_in,
                              void* d_out, int out_size, void* d_ws, size_t ws_size,
                              hipStream_t stream) {
    const float* x       = (const float*)d_in[0];
    const float* coeffs  = (const float*)d_in[1];
    const float* base_w  = (const float*)d_in[2];
    _Float16* W4 = (_Float16*)d_ws;   // 2 halves x 144 KB = 294912 bytes

    static int attr_done = 0;
    (void)attr_done;  // hipFuncSetAttribute is idempotent & capture-safe
    hipFuncSetAttribute((const void*)kan_main,
                        hipFuncAttributeMaxDynamicSharedMemorySize, 147456);

    kan_prep<<<dim3(72), dim3(256), 0, stream>>>(coeffs, base_w, W4);
    kan_main<<<dim3(BATCH / 256), dim3(512), 147456, stream>>>(x, W4, (float*)d_out);
}